// Round 13
// baseline (56.131 us; speedup 1.0000x reference)
//
#include <hip/hip_runtime.h>

// NNLoss: min over 5x5 shifted neighborhoods of channel-summed L1 distance,
// then global mean. B=16, C=3, H=W=512, fp32.
// R13: R11 skeleton (TW=256 tiles, GW=268, coalesced loads, 2 blocks/CU) +
// fused last-block tail (no 2nd launch) + interior staging fast path (no
// per-element selects; 60-thread PADV edge fixup). Boundary bands (0,31)
// keep the full select path.

#define PADV (-10000.0f)

constexpr int Bn = 16, Cn = 3, Hn = 512, Wn = 512;
constexpr long PLANE = (long)Hn * Wn;                  // 262144

constexpr int TW = 256, TH = 16;
constexpr int GW = 268;                                // 268 % 32 == 12
constexpr int GH = TH + 4;                             // 20 rows: h0-2..h0+17
constexpr int F4ROW = 66;                              // 264 floats: w0-4..w0+259
constexpr int F4T = Cn * GH * F4ROW;                   // 3960
constexpr int BLOCK = 512;
constexpr int SR = 8;                                  // ceil(3960/512)
constexpr int NBLOCKS = Bn * 2 * (Hn / TH);            // 1024

__global__ __launch_bounds__(BLOCK, 2) void nnloss_fused(
    const float* __restrict__ pred, const float* __restrict__ gt,
    float* __restrict__ out, float* __restrict__ ws) {
  unsigned int* cnt = (unsigned int*)ws;
  volatile float* partial = ws + 64;

  // bijective XCD swizzle: each XCD owns 128 consecutive wg
  const int wg = ((blockIdx.x & 7) << 7) | (blockIdx.x >> 3);
  const int band = wg & 31;
  const int tw = (wg >> 5) & 1;
  const int b = wg >> 6;
  const int w0 = tw * TW;
  const int h0 = band * TH;

  __shared__ __align__(16) float tile[Cn][GH][GW];     // 64,320 B

  const float* gb = gt + (long)b * Cn * PLANE;
  const float* pb = pred + (long)b * Cn * PLANE;

  const int tid = threadIdx.x;
  const int tx = tid & 31;                             // 32 strips of 8 px
  const int ty = tid >> 5;                             // 16 rows

  // ---- stage gt: gather all loads, then write ----
  float4 sv[SR];
  const bool rowsafe = (h0 >= 2) && (h0 + TH + 2 <= Hn);
  if (rowsafe) {
#pragma unroll
    for (int m = 0; m < SR; ++m) {
      const int idx = tid + m * BLOCK;
      if (m < 7 || idx < F4T) {
        const int c = idx / (GH * F4ROW);
        const int rem = idx - c * (GH * F4ROW);
        const int r = rem / F4ROW;
        const int k = rem - r * F4ROW;
        const int gcc = min(max(4 * k - 4, 0), Wn - 4); // only k=0/65 clamp
        sv[m] = *(const float4*)(gb + (long)c * PLANE +
                                 (long)(h0 - 2 + r) * Wn + gcc);
      }
    }
  } else {
#pragma unroll
    for (int m = 0; m < SR; ++m) {
      const int idx = tid + m * BLOCK;
      if (m < 7 || idx < F4T) {
        const int c = idx / (GH * F4ROW);
        const int rem = idx - c * (GH * F4ROW);
        const int r = rem / F4ROW;
        const int k = rem - r * F4ROW;
        const int ghc = min(max(h0 - 2 + r, 0), Hn - 1);
        const int gcc = min(max(4 * k - 4, 0), Wn - 4);
        sv[m] = *(const float4*)(gb + (long)c * PLANE + (long)ghc * Wn + gcc);
      }
    }
  }

  // ---- pred: 8 px/thread, coalesced (tx fast), issued before writes ----
  float p[Cn][8];
  {
    const float* pp = pb + (long)(h0 + ty) * Wn + (w0 + 8 * tx);
#pragma unroll
    for (int c = 0; c < Cn; ++c) {
      const float4 v0 = *(const float4*)(pp + (long)c * PLANE);
      const float4 v1 = *(const float4*)(pp + (long)c * PLANE + 4);
      p[c][0] = v0.x; p[c][1] = v0.y; p[c][2] = v0.z; p[c][3] = v0.w;
      p[c][4] = v1.x; p[c][5] = v1.y; p[c][6] = v1.z; p[c][7] = v1.w;
    }
  }

  // ---- writes ----
  if (rowsafe) {
#pragma unroll
    for (int m = 0; m < SR; ++m) {
      const int idx = tid + m * BLOCK;
      if (m < 7 || idx < F4T) {
        const int c = idx / (GH * F4ROW);
        const int rem = idx - c * (GH * F4ROW);
        const int r = rem / F4ROW;
        const int k = rem - r * F4ROW;
        *(float4*)&tile[c][r][4 * k] = sv[m];
      }
    }
    // edge fixup: fully-OOB f4 at k=0 (tw=0) or k=65 (tw=1)
    if (tid < Cn * GH) {
      const int c = tid / GH;
      const int r = tid - c * GH;
      const int L = (tw == 0) ? 0 : 260;
      *(float4*)&tile[c][r][L] = make_float4(PADV, PADV, PADV, PADV);
    }
  } else {
#pragma unroll
    for (int m = 0; m < SR; ++m) {
      const int idx = tid + m * BLOCK;
      if (m < 7 || idx < F4T) {
        const int c = idx / (GH * F4ROW);
        const int rem = idx - c * (GH * F4ROW);
        const int r = rem / F4ROW;
        const int k = rem - r * F4ROW;
        const int gh = h0 - 2 + r;
        const int gc0 = w0 - 4 + 4 * k;
        const bool rb = (gh < 0) || (gh >= Hn);
        float4 v = sv[m];
        v.x = (rb || gc0 + 0 < 0 || gc0 + 0 >= Wn) ? PADV : v.x;
        v.y = (rb || gc0 + 1 < 0 || gc0 + 1 >= Wn) ? PADV : v.y;
        v.z = (rb || gc0 + 2 < 0 || gc0 + 2 >= Wn) ? PADV : v.z;
        v.w = (rb || gc0 + 3 < 0 || gc0 + 3 >= Wn) ? PADV : v.w;
        *(float4*)&tile[c][r][4 * k] = v;
      }
    }
  }
  __syncthreads();

  // ---- compute: window cols L = 8tx+2 .. 8tx+13 (g[q+dj+2]) ----
  float m8[8];
#pragma unroll
  for (int q = 0; q < 8; ++q) m8[q] = 3.0e38f;

#pragma unroll
  for (int di = 0; di < 5; ++di) {
    float s[5][8];
    float g[14];
#pragma unroll
    for (int c = 0; c < Cn; ++c) {
      const float* base = &tile[c][ty + di][8 * tx];
      const float2 e0 = *(const float2*)(base + 2);
      const float4 A = *(const float4*)(base + 4);
      const float4 B2 = *(const float4*)(base + 8);
      const float2 e1 = *(const float2*)(base + 12);
      g[2] = e0.x;  g[3] = e0.y;
      g[4] = A.x;   g[5] = A.y;   g[6] = A.z;   g[7] = A.w;
      g[8] = B2.x;  g[9] = B2.y;  g[10] = B2.z; g[11] = B2.w;
      g[12] = e1.x; g[13] = e1.y;
      if (c == 0) {
#pragma unroll
        for (int dj = 0; dj < 5; ++dj)
#pragma unroll
          for (int q = 0; q < 8; ++q)
            s[dj][q] = fabsf(g[q + dj + 2] - p[0][q]);
      } else {
#pragma unroll
        for (int dj = 0; dj < 5; ++dj)
#pragma unroll
          for (int q = 0; q < 8; ++q)
            s[dj][q] += fabsf(g[q + dj + 2] - p[c][q]);
      }
    }
#pragma unroll
    for (int q = 0; q < 8; ++q) {
      const float t1 = fminf(fminf(s[0][q], s[1][q]), s[2][q]);   // v_min3
      const float t2 = fminf(fminf(t1, s[3][q]), s[4][q]);        // v_min3
      m8[q] = fminf(m8[q], t2);
    }
  }

  float v = ((m8[0] + m8[1]) + (m8[2] + m8[3])) +
            ((m8[4] + m8[5]) + (m8[6] + m8[7]));

  // ---- block reduction ----
#pragma unroll
  for (int off = 32; off > 0; off >>= 1) v += __shfl_down(v, off, 64);
  __shared__ float wsum[BLOCK / 64];
  __shared__ bool slast;
  const int lane = tid & 63;
  const int wid = tid >> 6;
  if (lane == 0) wsum[wid] = v;
  __syncthreads();
  if (tid == 0) {
    float tsum = 0.f;
#pragma unroll
    for (int i = 0; i < BLOCK / 64; ++i) tsum += wsum[i];
    partial[wg] = tsum;
    __threadfence();                                   // publish partial
    const unsigned o = atomicAdd(cnt, 1u);             // device-scope
    slast = (o == (unsigned)(NBLOCKS - 1));
  }
  __syncthreads();

  // ---- fused tail: last block reduces all partials in fixed order ----
  if (slast) {
    __threadfence();                                   // acquire
    double acc = (double)partial[tid] + (double)partial[tid + BLOCK];
#pragma unroll
    for (int off = 32; off > 0; off >>= 1) acc += __shfl_down(acc, off, 64);
    __shared__ double sd[BLOCK / 64];
    if (lane == 0) sd[wid] = acc;
    __syncthreads();
    if (tid == 0) {
      double tot = 0.0;
#pragma unroll
      for (int i = 0; i < BLOCK / 64; ++i) tot += sd[i];
      out[0] = (float)(tot / ((double)Bn * Hn * Wn));
    }
  }
}

extern "C" void kernel_launch(void* const* d_in, const int* in_sizes, int n_in,
                              void* d_out, int out_size, void* d_ws, size_t ws_size,
                              hipStream_t stream) {
  const float* pred = (const float*)d_in[0];
  const float* gt = (const float*)d_in[1];
  // d_in[2], d_in[3] are nh=5, nw=5 (hard-coded)
  float* out = (float*)d_out;
  float* ws = (float*)d_ws;  // [0..63]: counter, [64..64+1024): partials

  hipMemsetAsync(d_ws, 0, 256, stream);                // zero the counter
  nnloss_fused<<<NBLOCKS, BLOCK, 0, stream>>>(pred, gt, out, ws);
}

// Round 14
// 28.942 us; speedup vs baseline: 1.9394x; 1.9394x over previous
//
#include <hip/hip_runtime.h>

// NNLoss: min over 5x5 shifted neighborhoods of channel-summed L1 distance,
// then global mean. B=16, C=3, H=W=512, fp32.
// R14: R11 skeleton (TW=256, GW=268, XCD swizzle, 2 kernels, NO fences —
// R12/R13's threadfence tail poisoned L2) + interior staging fast path +
// 2-row ownership (4px x 2 rows/thread, row-uniform waves -> 32-bank-optimal
// b128 reads, LDS rows reused for both output rows).

#define PADV (-10000.0f)

constexpr int Bn = 16, Cn = 3, Hn = 512, Wn = 512;
constexpr long PLANE = (long)Hn * Wn;                  // 262144

constexpr int TW = 256, TH = 16;
constexpr int GW = 268;                                // 268 % 32 == 12
constexpr int GH = TH + 4;                             // 20 rows: h0-2..h0+17
constexpr int F4ROW = 66;                              // 264 floats: w0-4..w0+259
constexpr int F4T = Cn * GH * F4ROW;                   // 3960
constexpr int BLOCK = 512;
constexpr int NBLOCKS = Bn * 2 * (Hn / TH);            // 1024

__global__ __launch_bounds__(BLOCK, 2) void nnloss_main(
    const float* __restrict__ pred, const float* __restrict__ gt,
    float* __restrict__ partial) {
  // bijective XCD swizzle: each XCD owns 128 consecutive wg
  const int wg = ((blockIdx.x & 7) << 7) | (blockIdx.x >> 3);
  const int band = wg & 31;
  const int tw = (wg >> 5) & 1;
  const int b = wg >> 6;
  const int w0 = tw * TW;
  const int h0 = band * TH;

  __shared__ __align__(16) float tile[Cn][GH][GW];     // 64,320 B

  const float* gb = gt + (long)b * Cn * PLANE;
  const float* pb = pred + (long)b * Cn * PLANE;

  const int tid = threadIdx.x;
  const bool rowsafe = (h0 >= 2) && (h0 + TH + 2 <= Hn);

  // ---- stage gt: two gather-then-write halves (sv[4] regs each) ----
  if (rowsafe) {
#pragma unroll
    for (int half = 0; half < 2; ++half) {
      float4 sv[4];
#pragma unroll
      for (int m = 0; m < 4; ++m) {
        const int idx = tid + (half * 4 + m) * BLOCK;
        if (half == 0 || m < 3 || idx < F4T) {
          const int c = idx / (GH * F4ROW);
          const int rem = idx - c * (GH * F4ROW);
          const int r = rem / F4ROW;
          const int k = rem - r * F4ROW;
          const int gcc = min(max(4 * k - 4, 0), Wn - 4);
          sv[m] = *(const float4*)(gb + (long)c * PLANE +
                                   (long)(h0 - 2 + r) * Wn + (w0 - TW * tw ? 0 : 0) + gcc + (long)0);
        }
      }
#pragma unroll
      for (int m = 0; m < 4; ++m) {
        const int idx = tid + (half * 4 + m) * BLOCK;
        if (half == 0 || m < 3 || idx < F4T) {
          const int c = idx / (GH * F4ROW);
          const int rem = idx - c * (GH * F4ROW);
          const int r = rem / F4ROW;
          const int k = rem - r * F4ROW;
          *(float4*)&tile[c][r][4 * k] = sv[m];
        }
      }
    }
    // fully-OOB edge f4: k=0 (tw=0) or k=65 (tw=1)
    if (tid < Cn * GH) {
      const int c = tid / GH;
      const int r = tid - c * GH;
      const int L = (tw == 0) ? 0 : 260;
      *(float4*)&tile[c][r][L] = make_float4(PADV, PADV, PADV, PADV);
    }
  } else {
#pragma unroll
    for (int half = 0; half < 2; ++half) {
      float4 sv[4];
#pragma unroll
      for (int m = 0; m < 4; ++m) {
        const int idx = tid + (half * 4 + m) * BLOCK;
        if (half == 0 || m < 3 || idx < F4T) {
          const int c = idx / (GH * F4ROW);
          const int rem = idx - c * (GH * F4ROW);
          const int r = rem / F4ROW;
          const int k = rem - r * F4ROW;
          const int ghc = min(max(h0 - 2 + r, 0), Hn - 1);
          const int gcc = min(max(4 * k - 4, 0), Wn - 4);
          sv[m] = *(const float4*)(gb + (long)c * PLANE + (long)ghc * Wn + gcc);
        }
      }
#pragma unroll
      for (int m = 0; m < 4; ++m) {
        const int idx = tid + (half * 4 + m) * BLOCK;
        if (half == 0 || m < 3 || idx < F4T) {
          const int c = idx / (GH * F4ROW);
          const int rem = idx - c * (GH * F4ROW);
          const int r = rem / F4ROW;
          const int k = rem - r * F4ROW;
          const int gh = h0 - 2 + r;
          const int gc0 = w0 - 4 + 4 * k - w0;         // = 4k-4 (tile-local)
          const int gcg = w0 + gc0;                    // global col of .x
          const bool rb = (gh < 0) || (gh >= Hn);
          float4 v = sv[m];
          v.x = (rb || gcg + 0 < 0 || gcg + 0 >= Wn) ? PADV : v.x;
          v.y = (rb || gcg + 1 < 0 || gcg + 1 >= Wn) ? PADV : v.y;
          v.z = (rb || gcg + 2 < 0 || gcg + 2 >= Wn) ? PADV : v.z;
          v.w = (rb || gcg + 3 < 0 || gcg + 3 >= Wn) ? PADV : v.w;
          *(float4*)&tile[c][r][4 * k] = v;
        }
      }
    }
  }

  // ---- pred: 4 px x 2 rows per thread; tx fast (coalesced) ----
  const int tx = tid & 63;                             // 64 strips of 4 px
  const int tyg = tid >> 6;                            // 8 row-pairs
  const int row0 = 2 * tyg;

  float p[2][Cn][4];
  {
    const float* pp = pb + (long)(h0 + row0) * Wn + (w0 + 4 * tx);
#pragma unroll
    for (int r = 0; r < 2; ++r)
#pragma unroll
      for (int c = 0; c < Cn; ++c) {
        const float4 v = *(const float4*)(pp + (long)c * PLANE + (long)r * Wn);
        p[r][c][0] = v.x; p[r][c][1] = v.y; p[r][c][2] = v.z; p[r][c][3] = v.w;
      }
  }

  __syncthreads();

  // ---- compute: LDS rows row0..row0+5 each read once, serve both rows ----
  float mm[2][4];
#pragma unroll
  for (int r = 0; r < 2; ++r)
#pragma unroll
    for (int q = 0; q < 4; ++q) mm[r][q] = 3.0e38f;

#pragma unroll
  for (int rowIdx = 0; rowIdx < 6; ++rowIdx) {
    const int lr = row0 + rowIdx;
    float g[Cn][10];
#pragma unroll
    for (int c = 0; c < Cn; ++c) {
      // window cols L = 4tx+2 .. 4tx+9 ; g[k] = col 4tx+k
      const float* base = &tile[c][lr][4 * tx];
      const float4 A = *(const float4*)(base);
      const float4 Bq = *(const float4*)(base + 4);
      const float2 Cq = *(const float2*)(base + 8);
      g[c][0] = A.x;  g[c][1] = A.y;  g[c][2] = A.z;  g[c][3] = A.w;
      g[c][4] = Bq.x; g[c][5] = Bq.y; g[c][6] = Bq.z; g[c][7] = Bq.w;
      g[c][8] = Cq.x; g[c][9] = Cq.y;
    }
#pragma unroll
    for (int r = 0; r < 2; ++r) {
      const int di = rowIdx - r;
      if (di < 0 || di > 4) continue;                  // compile-time pruned
      float s[5][4];
#pragma unroll
      for (int dj = 0; dj < 5; ++dj)
#pragma unroll
        for (int q = 0; q < 4; ++q)
          s[dj][q] = fabsf(g[0][q + dj + 2] - p[r][0][q]);
#pragma unroll
      for (int c = 1; c < Cn; ++c)
#pragma unroll
        for (int dj = 0; dj < 5; ++dj)
#pragma unroll
          for (int q = 0; q < 4; ++q)
            s[dj][q] += fabsf(g[c][q + dj + 2] - p[r][c][q]);
#pragma unroll
      for (int q = 0; q < 4; ++q) {
        const float t1 = fminf(fminf(s[0][q], s[1][q]), s[2][q]);  // v_min3
        const float t2 = fminf(fminf(t1, s[3][q]), s[4][q]);       // v_min3
        mm[r][q] = fminf(mm[r][q], t2);
      }
    }
  }

  float v = ((mm[0][0] + mm[0][1]) + (mm[0][2] + mm[0][3])) +
            ((mm[1][0] + mm[1][1]) + (mm[1][2] + mm[1][3]));

  // ---- block reduction ----
#pragma unroll
  for (int off = 32; off > 0; off >>= 1) v += __shfl_down(v, off, 64);
  __shared__ float wsum[BLOCK / 64];
  const int lane = tid & 63;
  const int wid = tid >> 6;
  if (lane == 0) wsum[wid] = v;
  __syncthreads();
  if (tid == 0) {
    float t = 0.f;
#pragma unroll
    for (int i = 0; i < BLOCK / 64; ++i) t += wsum[i];
    partial[blockIdx.x] = t;
  }
}

__global__ __launch_bounds__(256) void nnloss_reduce(
    const float* __restrict__ partial, float* __restrict__ out) {
  double acc = 0.0;
  for (int i = threadIdx.x; i < NBLOCKS; i += 256) acc += (double)partial[i];
#pragma unroll
  for (int off = 32; off > 0; off >>= 1) acc += __shfl_down(acc, off, 64);
  __shared__ double sd[4];
  const int lane = threadIdx.x & 63;
  const int wid = threadIdx.x >> 6;
  if (lane == 0) sd[wid] = acc;
  __syncthreads();
  if (threadIdx.x == 0) {
    const double tot = (sd[0] + sd[1]) + (sd[2] + sd[3]);
    out[0] = (float)(tot / ((double)Bn * Hn * Wn));
  }
}

extern "C" void kernel_launch(void* const* d_in, const int* in_sizes, int n_in,
                              void* d_out, int out_size, void* d_ws, size_t ws_size,
                              hipStream_t stream) {
  const float* pred = (const float*)d_in[0];
  const float* gt = (const float*)d_in[1];
  // d_in[2], d_in[3] are nh=5, nw=5 (hard-coded)
  float* out = (float*)d_out;
  float* partial = (float*)d_ws;  // 1024 floats = 4 KB

  nnloss_main<<<NBLOCKS, BLOCK, 0, stream>>>(pred, gt, partial);
  nnloss_reduce<<<1, 256, 0, stream>>>(partial, out);
}